// Round 2
// baseline (2184.957 us; speedup 1.0000x reference)
//
#include <hip/hip_runtime.h>
#include <hip/hip_bf16.h>
#include <hip/hip_fp16.h>

// Problem constants
#define B_SZ   8192
#define C_SZ   4096
#define G_SZ   8
#define HID_SZ 1024
#define CTRL_SZ 64
#define NGH    (G_SZ*HID_SZ)   // 8192

typedef _Float16 half8 __attribute__((ext_vector_type(8)));
typedef float f32x4 __attribute__((ext_vector_type(4)));

__device__ __forceinline__ void gload_lds16(const _Float16* g, _Float16* l){
    __builtin_amdgcn_global_load_lds((const __attribute__((address_space(1))) void*)g,
                                     (__attribute__((address_space(3))) void*)l, 16, 0, 0);
}

// ---------------- gate: choose = softmax(relu(y@wc1+bc1)@wc2+bc2) ----------------
__global__ void gate_kernel(const float* __restrict__ y, const float* __restrict__ wc1,
                            const float* __restrict__ bc1, const float* __restrict__ wc2,
                            const float* __restrict__ bc2, float* __restrict__ choose)
{
    int b = blockIdx.x*blockDim.x + threadIdx.x;
    if (b >= B_SZ) return;
    const float* yr = y + (long)b*CTRL_SZ;
    float t[G_SZ];
    #pragma unroll
    for (int j=0;j<G_SZ;j++) t[j] = bc1[j];
    for (int c=0;c<CTRL_SZ;c++){
        float yv = yr[c];
        #pragma unroll
        for (int j=0;j<G_SZ;j++) t[j] += yv * wc1[c*G_SZ + j];
    }
    #pragma unroll
    for (int j=0;j<G_SZ;j++) t[j] = fmaxf(t[j], 0.f);
    float gs[G_SZ];
    #pragma unroll
    for (int i=0;i<G_SZ;i++){
        float s = bc2[i];
        #pragma unroll
        for (int j=0;j<G_SZ;j++) s += t[j]*wc2[j*G_SZ + i];
        gs[i] = s;
    }
    float m = gs[0];
    #pragma unroll
    for (int i=1;i<G_SZ;i++) m = fmaxf(m, gs[i]);
    float den = 0.f;
    #pragma unroll
    for (int i=0;i<G_SZ;i++){ gs[i] = __expf(gs[i]-m); den += gs[i]; }
    float inv = 1.f/den;
    #pragma unroll
    for (int i=0;i<G_SZ;i++) choose[(long)b*G_SZ + i] = gs[i]*inv;
}

// ---------------- fp32 -> fp16 cast (coalesced, 8/thread) ----------------
__global__ void cast_f32_f16_k(const float* __restrict__ in, _Float16* __restrict__ out, long n)
{
    long i = ((long)blockIdx.x*blockDim.x + threadIdx.x)*8;
    if (i >= n) return;
    const float4* p = reinterpret_cast<const float4*>(in + i);
    float4 v0 = p[0], v1 = p[1];
    half8 h;
    h[0]=(_Float16)v0.x; h[1]=(_Float16)v0.y; h[2]=(_Float16)v0.z; h[3]=(_Float16)v0.w;
    h[4]=(_Float16)v1.x; h[5]=(_Float16)v1.y; h[6]=(_Float16)v1.z; h[7]=(_Float16)v1.w;
    *reinterpret_cast<half8*>(out + i) = h;
}

// ---------------- transpose-cast: per g, in[r][c] (f32) -> out[c*outRowStride + r] (f16) ----------------
__global__ void transpose_cast_k(const float* __restrict__ in, _Float16* __restrict__ out,
                                 int R, int C, long inGStride, long outGStride, long outRowStride)
{
    __shared__ float tile[32][33];
    int c0 = blockIdx.x*32, r0 = blockIdx.y*32;
    const float* ing = in + (long)blockIdx.z*inGStride;
    _Float16* outg = out + (long)blockIdx.z*outGStride;
    int tx = threadIdx.x & 31, ty = threadIdx.x >> 5;   // 32x8
    #pragma unroll
    for (int p=0;p<4;p++)
        tile[ty+p*8][tx] = ing[(long)(r0+ty+p*8)*C + c0 + tx];
    __syncthreads();
    #pragma unroll
    for (int p=0;p<4;p++)
        outg[(long)(c0+ty+p*8)*outRowStride + r0 + tx] = (_Float16)tile[tx][ty+p*8];
}

// ---------------- GEMM: C[M,N] = A[M,K] * Bt[N,K]^T  (fp16 in, fp32 acc) ----------------
// EPI==1: out fp16 = relu(acc + b1[n]) * choose[m, n>>10]     (writes outH, ld N)
// EPI==2: out fp32 = acc + sum_g choose[m,g]*b2[g,n]          (writes outF, ld N)
template<int EPI>
__global__ __launch_bounds__(256, 2)
void gemm_f16_k(const _Float16* __restrict__ A, const _Float16* __restrict__ Bt,
                int M, int N, int K,
                const float* __restrict__ bias1, const float* __restrict__ choose,
                const float* __restrict__ b2,
                _Float16* __restrict__ outH, float* __restrict__ outF)
{
    __shared__ __align__(16) _Float16 As[128*64];
    __shared__ __align__(16) _Float16 Bs[128*64];
    __shared__ float sCh[128*G_SZ];
    __shared__ float sB2[G_SZ*128];

    // XCD-aware tile swizzle (nwg % 8 == 0 for all our launches)
    int nbx = gridDim.x;
    int nwg = nbx*gridDim.y;
    int lin = blockIdx.y*nbx + blockIdx.x;
    int cpx = nwg >> 3;
    int swz = (lin & 7)*cpx + (lin >> 3);
    int row0 = (swz / nbx)*128;
    int col0 = (swz % nbx)*128;

    int tid = threadIdx.x;
    int wid = tid >> 6, lane = tid & 63;
    int l15 = lane & 15, l4 = lane >> 4;
    int wr = wid >> 1, wcc = wid & 1;

    // stage epilogue data (disjoint LDS regions; covered by K-loop barriers)
    for (int t = tid; t < 128*G_SZ; t += 256) sCh[t] = choose[(long)row0*G_SZ + t];
    if (EPI == 2){
        for (int t = tid; t < G_SZ*128; t += 256) sB2[t] = b2[(long)(t >> 7)*N + col0 + (t & 127)];
    }

    f32x4 zero = {0.f, 0.f, 0.f, 0.f};
    f32x4 acc[4][4];
    #pragma unroll
    for (int i=0;i<4;i++)
        #pragma unroll
        for (int j=0;j<4;j++) acc[i][j] = zero;

    const long aBase = (long)row0*K;
    const long bBase = (long)col0*K;
    const int nk = K >> 6;
    for (int kt = 0; kt < nk; ++kt){
        int k0 = kt << 6;
        #pragma unroll
        for (int r = 0; r < 4; ++r){
            int idx = r*256 + tid;
            int rr  = idx >> 3;          // row within 128-row tile
            int cc8 = (idx & 7) << 3;    // col (halfs) within 64-wide K-tile
            gload_lds16(A  + aBase + (long)rr*K + k0 + cc8, As + (r*256 + wid*64)*8);
            gload_lds16(Bt + bBase + (long)rr*K + k0 + cc8, Bs + (r*256 + wid*64)*8);
        }
        __syncthreads();
        #pragma unroll
        for (int ks = 0; ks < 2; ++ks){
            half8 av[4], bv[4];
            #pragma unroll
            for (int i=0;i<4;i++)
                av[i] = *reinterpret_cast<const half8*>(As + (wr*64 + i*16 + l15)*64 + ks*32 + l4*8);
            #pragma unroll
            for (int j=0;j<4;j++)
                bv[j] = *reinterpret_cast<const half8*>(Bs + (wcc*64 + j*16 + l15)*64 + ks*32 + l4*8);
            #pragma unroll
            for (int i=0;i<4;i++)
                #pragma unroll
                for (int j=0;j<4;j++)
                    acc[i][j] = __builtin_amdgcn_mfma_f32_16x16x32_f16(av[i], bv[j], acc[i][j], 0, 0, 0);
        }
        __syncthreads();
    }

    // epilogue: D[row=(lane>>4)*4+r][col=lane&15] per 16x16 frag (m89-verified mapping)
    #pragma unroll
    for (int j=0;j<4;j++){
        int lc = wcc*64 + j*16 + l15;
        long gc = col0 + lc;
        if (EPI == 1){
            float b1v = bias1[gc];
            int g = (int)(gc >> 10) & 7;
            #pragma unroll
            for (int i=0;i<4;i++){
                #pragma unroll
                for (int r=0;r<4;r++){
                    int lr = wr*64 + i*16 + l4*4 + r;
                    float v = acc[i][j][r] + b1v;
                    v = fmaxf(v, 0.f) * sCh[lr*G_SZ + g];
                    outH[(long)(row0 + lr)*N + gc] = (_Float16)v;
                }
            }
        } else {
            float bc[G_SZ];
            #pragma unroll
            for (int g=0; g<G_SZ; g++) bc[g] = sB2[g*128 + lc];
            #pragma unroll
            for (int i=0;i<4;i++){
                #pragma unroll
                for (int r=0;r<4;r++){
                    int lr = wr*64 + i*16 + l4*4 + r;
                    float bias = 0.f;
                    #pragma unroll
                    for (int g=0; g<G_SZ; g++) bias += sCh[lr*G_SZ + g]*bc[g];
                    outF[(long)(row0 + lr)*N + gc] = acc[i][j][r] + bias;
                }
            }
        }
    }
}

extern "C" void kernel_launch(void* const* d_in, const int* in_sizes, int n_in,
                              void* d_out, int out_size, void* d_ws, size_t ws_size,
                              hipStream_t stream)
{
    const float* x   = (const float*)d_in[0];
    const float* y   = (const float*)d_in[1];
    const float* w1  = (const float*)d_in[2];
    const float* b1  = (const float*)d_in[3];
    const float* w2  = (const float*)d_in[4];
    const float* b2  = (const float*)d_in[5];
    const float* wc1 = (const float*)d_in[6];
    const float* bc1 = (const float*)d_in[7];
    const float* wc2 = (const float*)d_in[8];
    const float* bc2 = (const float*)d_in[9];
    float* out = (float*)d_out;
    (void)in_sizes; (void)n_in; (void)out_size; (void)ws_size;

    // workspace layout — peak concurrent use 256.25 MB:
    //   [choose 256KB][slot0 64MB][slot1 64MB][H 128MB]
    // GEMM1 uses A1h(slot0) + W1T(slot1) -> H; afterwards slot0 is dead,
    // so W2T (for GEMM2) aliases slot0.
    char* ws = (char*)d_ws;
    float*    choose = (float*)ws;                                   // 256 KB
    _Float16* A1h    = (_Float16*)(ws + (1L<<18));                   // 64 MB  [B, C] f16
    _Float16* W1T    = (_Float16*)(ws + (1L<<18) + 1*(1L<<26));      // 64 MB  [NGH, C] f16 (B^T for GEMM1)
    _Float16* H      = (_Float16*)(ws + (1L<<18) + 2*(1L<<26));      // 128 MB [B, NGH] f16
    _Float16* W2T    = A1h;                                          // 64 MB  [C, NGH] f16 (aliases A1h)

    gate_kernel<<<B_SZ/256, 256, 0, stream>>>(y, wc1, bc1, wc2, bc2, choose);

    long nx = (long)B_SZ*C_SZ;
    cast_f32_f16_k<<<(int)(nx/8/256), 256, 0, stream>>>(x, A1h, nx);

    // w1[g][c][h] -> W1T[(g*1024+h)][c]: per-g transpose of [C_SZ][HID_SZ]
    dim3 g1(HID_SZ/32, C_SZ/32, G_SZ);
    transpose_cast_k<<<g1, 256, 0, stream>>>(w1, W1T, C_SZ, HID_SZ,
                                             (long)C_SZ*HID_SZ, (long)HID_SZ*C_SZ, (long)C_SZ);

    // GEMM1: H = relu(x @ W1 + b1) * choose   [8192 x 8192], K=4096
    dim3 gg1(NGH/128, B_SZ/128);
    gemm_f16_k<1><<<gg1, 256, 0, stream>>>(A1h, W1T, B_SZ, NGH, C_SZ,
                                           b1, choose, nullptr, H, nullptr);

    // w2[g][h][c] -> W2T[c][g*1024+h]: per-g transpose of [HID_SZ][C_SZ]
    // (runs after GEMM1 so it can reuse A1h's region)
    dim3 g2(C_SZ/32, HID_SZ/32, G_SZ);
    transpose_cast_k<<<g2, 256, 0, stream>>>(w2, W2T, HID_SZ, C_SZ,
                                             (long)HID_SZ*C_SZ, (long)HID_SZ, (long)NGH);

    // GEMM2: out = H @ W2 + sum_g choose*b2   [8192 x 4096], K=8192
    dim3 gg2(C_SZ/128, B_SZ/128);
    gemm_f16_k<2><<<gg2, 256, 0, stream>>>(H, W2T, B_SZ, C_SZ, NGH,
                                           nullptr, choose, b2, nullptr, out);
}